// Round 1
// baseline (328.241 us; speedup 1.0000x reference)
//
#include <hip/hip_runtime.h>

// Problem constants (from reference)
#define IN_FEATURES 4096
#define RANK 64
#define NUM_EXPERTS 8
#define KDIM 512          // NUM_EXPERTS * RANK (GEMM K)
#define TOKENS 16384      // B*S = 4*4096      (GEMM M)
#define SCALING 1.0f      // ALPHA / RANK = 64/64

// GEMM tile config (m97-style)
#define BM 128
#define BN 128
#define BK 64

typedef __bf16 bf16x8 __attribute__((ext_vector_type(8)));
typedef float f32x4 __attribute__((ext_vector_type(4)));

__device__ __forceinline__ unsigned short f2bf(float f) {
  union { float f; unsigned int u; } v; v.f = f;
  unsigned int u = v.u;
  u += 0x7fffu + ((u >> 16) & 1u);   // round-to-nearest-even
  return (unsigned short)(u >> 16);
}

__device__ __forceinline__ void gload_lds16(const unsigned short* g, unsigned short* l) {
  __builtin_amdgcn_global_load_lds(
      (const __attribute__((address_space(1))) void*)g,
      (__attribute__((address_space(3))) void*)l,
      16, 0, 0);
}

// q[t, k*RANK+r] = bf16(w[t,k] * p[t,r])   -- [TOKENS, KDIM] bf16
__global__ void __launch_bounds__(256) q_pack(const float* __restrict__ p,
                                              const float* __restrict__ w,
                                              unsigned short* __restrict__ q) {
  int t = blockIdx.x;            // token
  int i = threadIdx.x;           // pair index 0..255 (512 elems / 2)
  int k = i >> 5;                // expert
  int rp = (i & 31) * 2;         // rank pair base
  float wk = w[t * NUM_EXPERTS + k];
  float p0 = p[t * RANK + rp];
  float p1 = p[t * RANK + rp + 1];
  ushort2 o;
  o.x = f2bf(wk * p0);
  o.y = f2bf(wk * p1);
  *(ushort2*)&q[t * KDIM + k * RANK + rp] = o;
}

// Bt[d, k*RANK+r] = bf16(A[k,d,r] * mask[k,d,r] * SCALING)  -- [IN_FEATURES, KDIM] bf16
__global__ void __launch_bounds__(256) b_pack(const float* __restrict__ A,
                                              const float* __restrict__ mask,
                                              unsigned short* __restrict__ Bt) {
  int d = blockIdx.x;
  int i = threadIdx.x;
  int k = i >> 5;
  int rp = (i & 31) * 2;
  long src = ((long)k * IN_FEATURES + d) * RANK + rp;
  float a0 = A[src] * mask[src] * SCALING;
  float a1 = A[src + 1] * mask[src + 1] * SCALING;
  ushort2 o;
  o.x = f2bf(a0);
  o.y = f2bf(a1);
  *(ushort2*)&Bt[d * KDIM + k * RANK + rp] = o;
}

// C[M,N] = q[M,K] @ Bt[N,K]^T  (both operands K-contiguous, bf16; C fp32)
// 128x128 tile, BK=64, 4 waves (2x2 of 64x64), 4x4 MFMA 16x16x32 frags per wave.
// LDS chunk swizzle: 16B chunk c -> LDS byte c*16; row = c>>3, phys = c&7,
// logical k-chunk = phys ^ (row&7). Staging gathers the swizzled global
// address per lane (legal: global_load_lds LDS dest is base + lane*16, which
// mapping c = j*256 + tid satisfies within each wave).
__global__ void __launch_bounds__(256, 2) gemm_kernel(
    const unsigned short* __restrict__ q,   // [TOKENS, KDIM]
    const unsigned short* __restrict__ Bt,  // [IN_FEATURES, KDIM]
    float* __restrict__ out) {              // [TOKENS, IN_FEATURES]
  __shared__ __align__(16) unsigned short sA[BM * BK];  // 16 KiB
  __shared__ __align__(16) unsigned short sB[BN * BK];  // 16 KiB

  const int tid = threadIdx.x;
  const int lane = tid & 63;
  const int wid = tid >> 6;
  const int u = lane & 15;        // row-within-16 / output col
  const int quad = lane >> 4;     // k-quad / output row group
  const int wave_m = (wid >> 1) * 64;
  const int wave_n = (wid & 1) * 64;

  const int m0 = blockIdx.y * BM;
  const int n0 = blockIdx.x * BN;

  f32x4 acc[4][4];
#pragma unroll
  for (int i = 0; i < 4; ++i)
#pragma unroll
    for (int j = 0; j < 4; ++j)
      acc[i][j] = (f32x4){0.f, 0.f, 0.f, 0.f};

  const unsigned short* gA[4];
  const unsigned short* gB[4];
  unsigned short* lA[4];
  unsigned short* lB[4];
#pragma unroll
  for (int j = 0; j < 4; ++j) {
    int c = j * 256 + tid;            // 16B chunk index, 0..1023
    int row = c >> 3;                 // tile row
    int logc = (c & 7) ^ (row & 7);   // logical k-chunk this LDS slot holds
    gA[j] = q  + (long)(m0 + row) * KDIM + logc * 8;
    gB[j] = Bt + (long)(n0 + row) * KDIM + logc * 8;
    lA[j] = sA + c * 8;
    lB[j] = sB + c * 8;
  }

  for (int kt = 0; kt < KDIM; kt += BK) {
#pragma unroll
    for (int j = 0; j < 4; ++j) {
      gload_lds16(gA[j] + kt, lA[j]);
      gload_lds16(gB[j] + kt, lB[j]);
    }
    __syncthreads();   // emits s_waitcnt vmcnt(0) before s_barrier

#pragma unroll
    for (int ki = 0; ki < 2; ++ki) {   // two 16x16x32 steps cover BK=64
      bf16x8 af[4], bfr[4];
      const int physbase = ki * 4;
#pragma unroll
      for (int mi = 0; mi < 4; ++mi) {
        int row = wave_m + mi * 16 + u;
        int phys = (physbase + quad) ^ (u & 7);
        af[mi] = *(const bf16x8*)&sA[row * BK + phys * 8];
      }
#pragma unroll
      for (int ni = 0; ni < 4; ++ni) {
        int row = wave_n + ni * 16 + u;
        int phys = (physbase + quad) ^ (u & 7);
        bfr[ni] = *(const bf16x8*)&sB[row * BK + phys * 8];
      }
#pragma unroll
      for (int mi = 0; mi < 4; ++mi)
#pragma unroll
        for (int ni = 0; ni < 4; ++ni)
          acc[mi][ni] = __builtin_amdgcn_mfma_f32_16x16x32_bf16(
              af[mi], bfr[ni], acc[mi][ni], 0, 0, 0);
    }
    __syncthreads();   // protect LDS before next stage overwrites
  }

  // Epilogue: C/D layout col = lane&15, row = quad*4 + reg
#pragma unroll
  for (int mi = 0; mi < 4; ++mi) {
#pragma unroll
    for (int r = 0; r < 4; ++r) {
      int row = m0 + wave_m + mi * 16 + quad * 4 + r;
#pragma unroll
      for (int ni = 0; ni < 4; ++ni) {
        int col = n0 + wave_n + ni * 16 + u;
        out[(long)row * IN_FEATURES + col] = acc[mi][ni][r];
      }
    }
  }
}

extern "C" void kernel_launch(void* const* d_in, const int* in_sizes, int n_in,
                              void* d_out, int out_size, void* d_ws, size_t ws_size,
                              hipStream_t stream) {
  const float* p    = (const float*)d_in[0];  // [4,4096,64]
  const float* w    = (const float*)d_in[1];  // [4,4096,8]
  const float* A    = (const float*)d_in[2];  // [8,4096,64]
  const float* mask = (const float*)d_in[3];  // [8,4096,64]
  float* out = (float*)d_out;                 // [4,4096,4096]

  unsigned short* q  = (unsigned short*)d_ws;            // 16 MiB bf16 [TOKENS, KDIM]
  unsigned short* Bt = q + (size_t)TOKENS * KDIM;        //  4 MiB bf16 [IN_FEATURES, KDIM]

  q_pack<<<TOKENS, 256, 0, stream>>>(p, w, q);
  b_pack<<<IN_FEATURES, 256, 0, stream>>>(A, mask, Bt);

  dim3 grid(IN_FEATURES / BN, TOKENS / BM);
  gemm_kernel<<<grid, dim3(256), 0, stream>>>(q, Bt, out);
}